// Round 13
// baseline (635.761 us; speedup 1.0000x reference)
//
#include <hip/hip_runtime.h>
#include <math.h>

#define Bn 4
#define Cn 64
#define Ln 4096
#define CQ 16
#define NH 4
#define NB 32
#define EPSV 1e-5f

#define MAXS 384    // max bucket size (mean 128, sigma ~11)
#define CH2 64      // staged key chunk
#define KSTR 20     // ks row stride (floats)
#define VSTR 64     // vs row stride (floats)

#define QSZ   (Bn*Ln*CQ)      // 262144 floats
#define VSZ   (Bn*Ln*Cn)      // 1048576 floats
#define ACCSZ (Bn*Ln*Cn)
#define NBH   (Bn*NH)         // 16
#define LSUMSZ (NH*Bn*Ln)     // 65536 floats

// layout (float units): [q][k][v][acc x4|x1][lsum][ssum][ssq]; y overlays q/k/v
#define OFF_K   QSZ
#define OFF_V   (2*QSZ)
#define OFF_ACC (2*QSZ + VSZ)

#define LOG2E 1.44269504088896f

// 768 blocks: (pos-group of 64) x (row-third of 32); og owns 8 rows
__global__ __launch_bounds__(256) void proj_kernel(
        const float* __restrict__ x,
        const float* __restrict__ Wq, const float* __restrict__ bq,
        const float* __restrict__ Wk, const float* __restrict__ bk,
        const float* __restrict__ Wv, const float* __restrict__ bv,
        float* __restrict__ q, float* __restrict__ k, float* __restrict__ v) {
    __shared__ float sWt[Cn*32];   // [c][rr]: this third's 32 rows
    __shared__ float sb[32];
    int tid = threadIdx.x;
    int third = blockIdx.x % 3;
    int pg    = blockIdx.x / 3;
    int rbase = third * 32;
    for (int idx = tid; idx < Cn*32; idx += 256) {
        int rr = idx & 31, c = idx >> 5;
        int r = rbase + rr;
        float w;
        if (r < 16)      w = Wq[r*Cn + c];
        else if (r < 32) w = Wk[(r-16)*Cn + c];
        else             w = Wv[(r-32)*Cn + c];
        sWt[c*32 + rr] = w;
    }
    if (tid < 32) {
        int r = rbase + tid;
        sb[tid] = (r < 16) ? bq[r] : (r < 32 ? bk[r-16] : bv[r-32]);
    }
    __syncthreads();
    int p = tid & 63, og = tid >> 6;       // og uniform per wave
    int gp = pg * 64 + p;                  // flattened position b*L + l
    int b = gp >> 12, l = gp & (Ln - 1);
    const float* xp = &x[b*Cn*Ln + l];
    int rr0 = og * 8;
    float val[8];
    #pragma unroll
    for (int i = 0; i < 8; i++) val[i] = sb[rr0 + i];
    #pragma unroll
    for (int c0 = 0; c0 < Cn; c0 += 8) {
        float xv[8];
        #pragma unroll
        for (int i = 0; i < 8; i++) xv[i] = xp[(c0 + i)*Ln];   // coalesced in p
        #pragma unroll
        for (int i = 0; i < 8; i++) {
            const float* wrow = &sWt[(c0 + i)*32 + rr0];       // LDS broadcast
            #pragma unroll
            for (int j = 0; j < 8; j++) val[j] = fmaf(wrow[j], xv[i], val[j]);
        }
    }
    int f = third*8 + og*2;                // wave-uniform; never straddles q/k/v
    float4 t0 = make_float4(val[0], val[1], val[2], val[3]);
    float4 t1 = make_float4(val[4], val[5], val[6], val[7]);
    float4* q4 = (float4*)&q[gp*CQ];
    float4* k4 = (float4*)&k[gp*CQ];
    float4* v4 = (float4*)&v[gp*Cn];
    if (f < 4)      { q4[f]   = t0; q4[f+1] = t1; }
    else if (f < 8) { k4[f-4] = t0; k4[f-3] = t1; }
    else            { v4[f-8] = t0; v4[f-7] = t1; }
}

// sweep keys [j0,j1) for NS queries/quad (stride 64). MODE1: emit UNNORMALIZED
// partial o + lsum via atomics (key-split). MODE0: full keys, normalize, atomic.
template<int NS, int MODE>
__device__ __forceinline__ void attn_pass(
        int qbase, int S, int j0, int j1, int b, int h, int tid,
        const int* list, float* ks, float* vs,
        const float* __restrict__ q, const float* __restrict__ k,
        const float* __restrict__ v, float* __restrict__ acc,
        float* __restrict__ lsumBuf) {
    int qd = tid >> 2, c4 = tid & 3;
    float4 qr[NS][4];
    float4 o[NS][4];
    float lsum[NS];
    int qi[NS], iqr[NS];
    #pragma unroll
    for (int s = 0; s < NS; s++) {
        qi[s] = qbase + 64*s + qd;
        iqr[s] = 0;
        lsum[s] = 0.f;
        #pragma unroll
        for (int i = 0; i < 4; i++) o[s][i] = make_float4(0.f,0.f,0.f,0.f);
        if (qi[s] < S) {
            iqr[s] = list[qi[s]];
            const float4* qp = (const float4*)&q[((size_t)b*Ln + iqr[s])*CQ];
            #pragma unroll
            for (int i = 0; i < 4; i++) {
                float4 t = qp[i];   // pre-scale: exp(s) == exp2(s*log2e)
                t.x*=LOG2E; t.y*=LOG2E; t.z*=LOG2E; t.w*=LOG2E;
                qr[s][i] = t;
            }
        } else {
            #pragma unroll
            for (int i = 0; i < 4; i++) qr[s][i] = make_float4(0.f,0.f,0.f,0.f);
        }
    }
    for (int cc = j0; cc < j1; cc += CH2) {
        int nk = min(CH2, j1 - cc);
        __syncthreads();           // previous chunk fully consumed
        {   // stage K chunk: nk rows x 16 floats, one b128 per thread
            int jj = tid >> 2, cf = tid & 3;
            if (jj < nk) {
                const float4* kp = (const float4*)&k[((size_t)b*Ln + list[cc+jj])*CQ];
                *(float4*)&ks[jj*KSTR + cf*4] = kp[cf];
            }
        }
        #pragma unroll
        for (int uu = 0; uu < 4; uu++) {   // stage V chunk: nk rows x 64 floats
            int idx = uu*256 + tid;
            int jj = idx >> 4, cf = idx & 15;
            if (jj < nk) {
                const float4* vp = (const float4*)&v[((size_t)b*Ln + list[cc+jj])*Cn];
                *(float4*)&vs[jj*VSTR + cf*4] = vp[cf];
            }
        }
        __syncthreads();
        for (int j = 0; j < nk; j++) {
            const float4* kr = (const float4*)&ks[j*KSTR];   // broadcast
            float4 k0 = kr[0], k1 = kr[1], k2 = kr[2], k3 = kr[3];
            const float4* vp4 = (const float4*)&vs[j*VSTR + c4*16];
            float4 v0 = vp4[0], v1 = vp4[1], v2 = vp4[2], v3 = vp4[3];
            #pragma unroll
            for (int s = 0; s < NS; s++) {
                float s0 = qr[s][0].x*k0.x + qr[s][0].y*k0.y + qr[s][0].z*k0.z + qr[s][0].w*k0.w;
                float s1 = qr[s][1].x*k1.x + qr[s][1].y*k1.y + qr[s][1].z*k1.z + qr[s][1].w*k1.w;
                float s2 = qr[s][2].x*k2.x + qr[s][2].y*k2.y + qr[s][2].z*k2.z + qr[s][2].w*k2.w;
                float s3 = qr[s][3].x*k3.x + qr[s][3].y*k3.y + qr[s][3].z*k3.z + qr[s][3].w*k3.w;
                float pw = __builtin_amdgcn_exp2f((s0 + s1) + (s2 + s3));
                lsum[s] += pw;
                o[s][0].x = fmaf(pw, v0.x, o[s][0].x); o[s][0].y = fmaf(pw, v0.y, o[s][0].y);
                o[s][0].z = fmaf(pw, v0.z, o[s][0].z); o[s][0].w = fmaf(pw, v0.w, o[s][0].w);
                o[s][1].x = fmaf(pw, v1.x, o[s][1].x); o[s][1].y = fmaf(pw, v1.y, o[s][1].y);
                o[s][1].z = fmaf(pw, v1.z, o[s][1].z); o[s][1].w = fmaf(pw, v1.w, o[s][1].w);
                o[s][2].x = fmaf(pw, v2.x, o[s][2].x); o[s][2].y = fmaf(pw, v2.y, o[s][2].y);
                o[s][2].z = fmaf(pw, v2.z, o[s][2].z); o[s][2].w = fmaf(pw, v2.w, o[s][2].w);
                o[s][3].x = fmaf(pw, v3.x, o[s][3].x); o[s][3].y = fmaf(pw, v3.y, o[s][3].y);
                o[s][3].z = fmaf(pw, v3.z, o[s][3].z); o[s][3].w = fmaf(pw, v3.w, o[s][3].w);
            }
        }
    }
    #pragma unroll
    for (int s = 0; s < NS; s++) {
        if (qi[s] < S) {
            if (MODE == 1) {
                // unnormalized partials; both key-halves accumulate
                float* ap = &acc[((size_t)h*Bn*Ln + b*Ln + iqr[s])*Cn + c4*16];
                #pragma unroll
                for (int i = 0; i < 4; i++) {
                    atomicAdd(&ap[4*i+0], (&o[s][i].x)[0]);
                    atomicAdd(&ap[4*i+1], (&o[s][i].x)[1]);
                    atomicAdd(&ap[4*i+2], (&o[s][i].x)[2]);
                    atomicAdd(&ap[4*i+3], (&o[s][i].x)[3]);
                }
                if (c4 == 0)
                    atomicAdd(&lsumBuf[(size_t)h*Bn*Ln + b*Ln + iqr[s]], lsum[s]);
            } else {
                float inv = 1.f / lsum[s];
                #pragma unroll
                for (int i = 0; i < 4; i++) {
                    o[s][i].x*=inv; o[s][i].y*=inv; o[s][i].z*=inv; o[s][i].w*=inv;
                }
                float* ap = &acc[((size_t)b*Ln + iqr[s])*Cn + c4*16];
                #pragma unroll
                for (int i = 0; i < 4; i++) {
                    atomicAdd(&ap[4*i+0], (&o[s][i].x)[0]);
                    atomicAdd(&ap[4*i+1], (&o[s][i].x)[1]);
                    atomicAdd(&ap[4*i+2], (&o[s][i].x)[2]);
                    atomicAdd(&ap[4*i+3], (&o[s][i].x)[3]);
                }
            }
        }
    }
}

// MODE1: 1024 blocks, one per (bh,u,key-half). MODE0: 512 blocks, full keys.
template<int MODE>
__global__ __launch_bounds__(256, 4) void attn_kernel(
        const float* __restrict__ q, const float* __restrict__ k,
        const float* __restrict__ v, const int* __restrict__ hidx,
        float* __restrict__ acc, float* __restrict__ lsumBuf) {
    __shared__ int list[MAXS];
    __shared__ float ks[CH2*KSTR];
    __shared__ float vs[CH2*VSTR];
    __shared__ int wtot[4];
    int blk = blockIdx.x;
    int half = 0, rest = blk;
    if (MODE == 1) { half = blk & 1; rest = blk >> 1; }
    int u  = rest & (NB-1);
    int bh = rest >> 5;
    int b  = bh >> 2;
    int h  = bh & 3;
    int tid = threadIdx.x;

    // ---- deterministic ascending bucket list via wave scan ----
    const int4* hp4 = (const int4*)(&hidx[bh*Ln] + tid*16);
    int hv[16];
    #pragma unroll
    for (int t = 0; t < 4; t++) {
        int4 tmp = hp4[t];
        hv[t*4+0]=tmp.x; hv[t*4+1]=tmp.y; hv[t*4+2]=tmp.z; hv[t*4+3]=tmp.w;
    }
    int myCnt = 0;
    #pragma unroll
    for (int t = 0; t < 16; t++) myCnt += (hv[t] == u);
    int lane = tid & 63, wv = tid >> 6;
    int pre = myCnt;
    #pragma unroll
    for (int d = 1; d < 64; d <<= 1) {
        int t = __shfl_up(pre, d, 64);
        if (lane >= d) pre += t;
    }
    if (lane == 63) wtot[wv] = pre;
    __syncthreads();
    int base = 0;
    #pragma unroll
    for (int w = 0; w < 4; w++) base += (w < wv) ? wtot[w] : 0;
    int Sall = wtot[0] + wtot[1] + wtot[2] + wtot[3];
    int S = min(Sall, MAXS);
    int excl = base + pre - myCnt;
    #pragma unroll
    for (int t = 0; t < 16; t++) {
        if (hv[t] == u) {
            if (excl < MAXS) list[excl] = tid*16 + t;
            excl++;
        }
    }
    __syncthreads();

    int halfS = (S + 1) >> 1;
    int j0 = (MODE == 1) ? half * halfS : 0;
    int j1 = (MODE == 1) ? min(S, j0 + halfS) : S;

    // per-wave NS = ceil((S - qbase - wq0)/64), capped 3; 192 queries/sweep
    int wq0 = (tid >> 6) << 4;     // wave's first quad index
    for (int qbase = 0; qbase < S; qbase += 192) {
        int rem = S - qbase - wq0;
        // wave-uniform dispatch; all instances have identical barrier counts
        if (rem > 128)     attn_pass<3,MODE>(qbase,S,j0,j1,b,h,tid,list,ks,vs,q,k,v,acc,lsumBuf);
        else if (rem > 64) attn_pass<2,MODE>(qbase,S,j0,j1,b,h,tid,list,ks,vs,q,k,v,acc,lsumBuf);
        else               attn_pass<1,MODE>(qbase,S,j0,j1,b,h,tid,list,ks,vs,q,k,v,acc,lsumBuf);
    }
}

// 512 blocks: (pos-group of 64) x (channel half of 32); wave og handles 8 ch
template<int MODE>
__global__ __launch_bounds__(256) void outconv_kernel(
        const float* __restrict__ acc, const float* __restrict__ lsumBuf,
        const float* __restrict__ Wo, const float* __restrict__ bo,
        const float* __restrict__ gamma, const float* __restrict__ x,
        float* __restrict__ y) {
    __shared__ float sWt[Cn*32];   // [c][oo] this half's 32 channels
    __shared__ float sb[32];
    int tid = threadIdx.x;
    int half = blockIdx.x & 1;
    int pg   = blockIdx.x >> 1;
    for (int idx = tid; idx < Cn*32; idx += 256) {
        int oo = idx & 31, c = idx >> 5;
        sWt[c*32 + oo] = Wo[(half*32 + oo)*Cn + c];
    }
    if (tid < 32) sb[tid] = bo[half*32 + tid];
    __syncthreads();
    float g = gamma[0];
    int p = tid & 63, og = tid >> 6;
    int gp = pg * 64 + p;
    int b = gp >> 12, l = gp & (Ln - 1);
    int oo0 = og * 8;
    float val[8];
    #pragma unroll
    for (int i = 0; i < 8; i++) val[i] = sb[oo0 + i];
    float linv[4];
    if (MODE == 1) {
        #pragma unroll
        for (int hh = 0; hh < 4; hh++)
            linv[hh] = 0.25f / lsumBuf[(size_t)hh*Bn*Ln + gp];   // coalesced in p
    }
    const float4* ap0 = (const float4*)&acc[(size_t)gp*Cn];
    #pragma unroll
    for (int c4 = 0; c4 < 16; c4++) {
        float4 t;
        if (MODE == 1) {
            float4 t0 = ap0[c4];
            float4 t1 = ap0[(size_t)ACCSZ/4   + c4];
            float4 t2 = ap0[(size_t)ACCSZ/4*2 + c4];
            float4 t3 = ap0[(size_t)ACCSZ/4*3 + c4];
            t.x = t0.x*linv[0] + t1.x*linv[1] + t2.x*linv[2] + t3.x*linv[3];
            t.y = t0.y*linv[0] + t1.y*linv[1] + t2.y*linv[2] + t3.y*linv[3];
            t.z = t0.z*linv[0] + t1.z*linv[1] + t2.z*linv[2] + t3.z*linv[3];
            t.w = t0.w*linv[0] + t1.w*linv[1] + t2.w*linv[2] + t3.w*linv[3];
        } else {
            float4 t0 = ap0[c4];
            t.x = t0.x*0.25f; t.y = t0.y*0.25f; t.z = t0.z*0.25f; t.w = t0.w*0.25f;
        }
        float a0 = t.x, a1 = t.y, a2 = t.z, a3 = t.w;
        const float* w0 = &sWt[(c4*4+0)*32 + oo0];
        const float* w1 = &sWt[(c4*4+1)*32 + oo0];
        const float* w2 = &sWt[(c4*4+2)*32 + oo0];
        const float* w3 = &sWt[(c4*4+3)*32 + oo0];
        #pragma unroll
        for (int i = 0; i < 8; i++) {
            val[i] = fmaf(w0[i], a0, val[i]);
            val[i] = fmaf(w1[i], a1, val[i]);
            val[i] = fmaf(w2[i], a2, val[i]);
            val[i] = fmaf(w3[i], a3, val[i]);
        }
    }
    #pragma unroll
    for (int i = 0; i < 8; i++) {
        int o = half*32 + oo0 + i;
        float yv = fmaf(g, val[i], x[(b*Cn + o)*Ln + l]);
        y[(b*Cn + o)*Ln + l] = yv;             // coalesced in p
    }
}

__global__ __launch_bounds__(256) void stats_kernel(
        const float* __restrict__ y, float* __restrict__ ssum, float* __restrict__ ssq) {
    int c = blockIdx.x >> 2;       // channel
    int part = blockIdx.x & 3;     // batch index
    int tid = threadIdx.x;
    const float4* yp = (const float4*)&y[(part*Cn + c)*Ln];
    float s = 0.f, s2 = 0.f;
    #pragma unroll
    for (int i = 0; i < 4; i++) {
        float4 t = yp[i*256 + tid];
        s  += t.x + t.y + t.z + t.w;
        s2 += t.x*t.x + t.y*t.y + t.z*t.z + t.w*t.w;
    }
    #pragma unroll
    for (int w = 1; w < 64; w <<= 1) {
        s  += __shfl_xor(s,  w, 64);
        s2 += __shfl_xor(s2, w, 64);
    }
    __shared__ float rs[4], rs2[4];
    int wv = tid >> 6;
    if ((tid & 63) == 0) { rs[wv] = s; rs2[wv] = s2; }
    __syncthreads();
    if (tid == 0) {
        atomicAdd(&ssum[c], rs[0]+rs[1]+rs[2]+rs[3]);
        atomicAdd(&ssq[c],  rs2[0]+rs2[1]+rs2[2]+rs2[3]);
    }
}

__global__ __launch_bounds__(256) void norm_kernel(
        const float* __restrict__ y,
        const float* __restrict__ ssum, const float* __restrict__ ssq,
        const float* __restrict__ bnw, const float* __restrict__ bnb,
        float* __restrict__ out) {
    int idx = blockIdx.x * 256 + threadIdx.x;  // float4 index
    int flat = idx * 4;
    int c = (flat / Ln) & 63;
    const float n = (float)(Bn*Ln);
    float mu = ssum[c] / n;
    float var = ssq[c] / n - mu*mu;
    float is = rsqrtf(var + EPSV);
    float w = is * bnw[c];
    float bb = bnb[c] - mu * w;
    float4 t = ((const float4*)y)[idx];
    float4 r;
    r.x = t.x*w + bb; r.y = t.y*w + bb; r.z = t.z*w + bb; r.w = t.w*w + bb;
    ((float4*)out)[idx] = r;
}

extern "C" void kernel_launch(void* const* d_in, const int* in_sizes, int n_in,
                              void* d_out, int out_size, void* d_ws, size_t ws_size,
                              hipStream_t stream) {
    const float* x    = (const float*)d_in[0];
    const int*   hidx = (const int*)  d_in[1];
    const float* Wq   = (const float*)d_in[2];
    const float* bq   = (const float*)d_in[3];
    const float* Wk   = (const float*)d_in[4];
    const float* bk   = (const float*)d_in[5];
    const float* Wv   = (const float*)d_in[6];
    const float* bv   = (const float*)d_in[7];
    const float* Wo   = (const float*)d_in[8];
    const float* bo   = (const float*)d_in[9];
    const float* gam  = (const float*)d_in[10];
    const float* bnw  = (const float*)d_in[11];
    const float* bnb  = (const float*)d_in[12];
    float* out = (float*)d_out;

    float* ws  = (float*)d_ws;
    float* q   = ws;
    float* k   = ws + OFF_K;
    float* v   = ws + OFF_V;
    float* acc = ws + OFF_ACC;
    float* y   = ws;            // overlays q/k/v after attn

    // big: 4 hash acc buffers + lsum (key-split, partial-softmax path)
    const size_t bigNeed = ((size_t)OFF_ACC + 4*(size_t)ACCSZ + LSUMSZ + 2*Cn) * sizeof(float);
    bool big = ws_size >= bigNeed;
    float* lsumB = acc + (big ? 4*(size_t)ACCSZ : (size_t)ACCSZ);
    float* ssum  = lsumB + (big ? LSUMSZ : 0);
    float* ssq   = ssum + Cn;

    hipMemsetAsync(ssum, 0, 2*Cn*sizeof(float), stream);
    proj_kernel<<<Bn*Ln/64*3, 256, 0, stream>>>(x, Wq, bq, Wk, bk, Wv, bv, q, k, v);
    if (big) {
        hipMemsetAsync(acc, 0, (4*(size_t)ACCSZ + LSUMSZ)*sizeof(float), stream);
        attn_kernel<1><<<NBH*NB*2, 256, 0, stream>>>(q, k, v, hidx, acc, lsumB);
        outconv_kernel<1><<<Bn*Ln/64*2, 256, 0, stream>>>(acc, lsumB, Wo, bo, gam, x, y);
    } else {
        hipMemsetAsync(acc, 0, (size_t)ACCSZ*sizeof(float), stream);
        attn_kernel<0><<<NBH*NB, 256, 0, stream>>>(q, k, v, hidx, acc, lsumB);
        outconv_kernel<0><<<Bn*Ln/64*2, 256, 0, stream>>>(acc, lsumB, Wo, bo, gam, x, y);
    }
    stats_kernel<<<Cn*4, 256, 0, stream>>>(y, ssum, ssq);
    norm_kernel<<<Bn*Cn*Ln/4/256, 256, 0, stream>>>(y, ssum, ssq, bnw, bnb, out);
}

// Round 14
// 200.224 us; speedup vs baseline: 3.1752x; 3.1752x over previous
//
#include <hip/hip_runtime.h>
#include <math.h>

#define Bn 4
#define Cn 64
#define Ln 4096
#define CQ 16
#define NH 4
#define NB 32
#define EPSV 1e-5f

#define MAXS 384    // max bucket size (mean 128, sigma ~11)
#define CH2 128     // staged key chunk (both halves' rows)
#define KSTR 20     // ks row stride (floats)
#define VSTR 64     // vs row stride (floats)

#define QSZ   (Bn*Ln*CQ)      // 262144 floats
#define VSZ   (Bn*Ln*Cn)      // 1048576 floats
#define ACCSZ (Bn*Ln*Cn)
#define NBH   (Bn*NH)         // 16

// layout (float units): [q][k][v][acc x4|x1][ssumP(256)][ssqP(256)]
#define OFF_K   QSZ
#define OFF_V   (2*QSZ)
#define OFF_ACC (2*QSZ + VSZ)

#define LOG2E 1.44269504088896f

// 768 blocks: (pos-group of 64) x (row-third of 32); og owns 8 rows
__global__ __launch_bounds__(256) void proj_kernel(
        const float* __restrict__ x,
        const float* __restrict__ Wq, const float* __restrict__ bq,
        const float* __restrict__ Wk, const float* __restrict__ bk,
        const float* __restrict__ Wv, const float* __restrict__ bv,
        float* __restrict__ q, float* __restrict__ k, float* __restrict__ v) {
    __shared__ float sWt[Cn*32];   // [c][rr]: this third's 32 rows
    __shared__ float sb[32];
    int tid = threadIdx.x;
    int third = blockIdx.x % 3;
    int pg    = blockIdx.x / 3;
    int rbase = third * 32;
    for (int idx = tid; idx < Cn*32; idx += 256) {
        int rr = idx & 31, c = idx >> 5;
        int r = rbase + rr;
        float w;
        if (r < 16)      w = Wq[r*Cn + c];
        else if (r < 32) w = Wk[(r-16)*Cn + c];
        else             w = Wv[(r-32)*Cn + c];
        sWt[c*32 + rr] = w;
    }
    if (tid < 32) {
        int r = rbase + tid;
        sb[tid] = (r < 16) ? bq[r] : (r < 32 ? bk[r-16] : bv[r-32]);
    }
    __syncthreads();
    int p = tid & 63, og = tid >> 6;       // og uniform per wave
    int gp = pg * 64 + p;                  // flattened position b*L + l
    int b = gp >> 12, l = gp & (Ln - 1);
    const float* xp = &x[b*Cn*Ln + l];
    int rr0 = og * 8;
    float val[8];
    #pragma unroll
    for (int i = 0; i < 8; i++) val[i] = sb[rr0 + i];
    #pragma unroll
    for (int c0 = 0; c0 < Cn; c0 += 8) {
        float xv[8];
        #pragma unroll
        for (int i = 0; i < 8; i++) xv[i] = xp[(c0 + i)*Ln];   // coalesced in p
        #pragma unroll
        for (int i = 0; i < 8; i++) {
            const float* wrow = &sWt[(c0 + i)*32 + rr0];       // LDS broadcast
            #pragma unroll
            for (int j = 0; j < 8; j++) val[j] = fmaf(wrow[j], xv[i], val[j]);
        }
    }
    int f = third*8 + og*2;                // wave-uniform; never straddles q/k/v
    float4 t0 = make_float4(val[0], val[1], val[2], val[3]);
    float4 t1 = make_float4(val[4], val[5], val[6], val[7]);
    float4* q4 = (float4*)&q[gp*CQ];
    float4* k4 = (float4*)&k[gp*CQ];
    float4* v4 = (float4*)&v[gp*Cn];
    if (f < 4)      { q4[f]   = t0; q4[f+1] = t1; }
    else if (f < 8) { k4[f-4] = t0; k4[f-3] = t1; }
    else            { v4[f-8] = t0; v4[f-7] = t1; }
}

// One qbase pass. 8 waves: half = wave>>2 sweeps staged rows [half*64, ...).
// Paired waves (w, w+4) hold the same NS query slots; partials merged via LDS.
// Barrier counts identical across all waves (NS is pair-uniform; 2-round merge).
template<int NS, int MODE>
__device__ __forceinline__ void attn_pass(
        int qbase, int S, int b, int h, int half, int rem, int tid,
        const int* list, float* ks, float* vs, float* lsm,
        const float* __restrict__ q, const float* __restrict__ k,
        const float* __restrict__ v, float* __restrict__ acc) {
    int qd = (tid >> 2) & 63;      // query quad (0..63), same for paired waves
    int c4 = tid & 3;              // channel quarter
    int mx = tid & 255;            // merge exchange slot
    float4 qr[NS][4];
    float4 o[NS][4];
    float lsum[NS];
    int qi[NS], iqr[NS];
    #pragma unroll
    for (int s = 0; s < NS; s++) {
        qi[s] = qbase + 64*s + qd;
        iqr[s] = 0;
        lsum[s] = 0.f;
        #pragma unroll
        for (int i = 0; i < 4; i++) o[s][i] = make_float4(0.f,0.f,0.f,0.f);
        if (qi[s] < S) {
            iqr[s] = list[qi[s]];
            const float4* qp = (const float4*)&q[((size_t)b*Ln + iqr[s])*CQ];
            #pragma unroll
            for (int i = 0; i < 4; i++) {
                float4 t = qp[i];   // pre-scale: exp(s) == exp2(s*log2e)
                t.x*=LOG2E; t.y*=LOG2E; t.z*=LOG2E; t.w*=LOG2E;
                qr[s][i] = t;
            }
        } else {
            #pragma unroll
            for (int i = 0; i < 4; i++) qr[s][i] = make_float4(0.f,0.f,0.f,0.f);
        }
    }
    for (int cc = 0; cc < S; cc += CH2) {
        int nk = min(CH2, S - cc);
        __syncthreads();           // previous chunk / merge buffer free
        {   // stage K chunk: 128 rows x 4 f4 = 1 f4/thread
            int jj = tid >> 2, cf = tid & 3;
            if (jj < nk) {
                const float4* kp = (const float4*)&k[((size_t)b*Ln + list[cc+jj])*CQ];
                *(float4*)&ks[jj*KSTR + cf*4] = kp[cf];
            }
        }
        #pragma unroll
        for (int uu = 0; uu < 4; uu++) {   // stage V chunk: 128 rows x 16 f4
            int idx = uu*512 + tid;
            int jj = idx >> 4, cf = idx & 15;
            if (jj < nk) {
                const float4* vp = (const float4*)&v[((size_t)b*Ln + list[cc+jj])*Cn];
                *(float4*)&vs[jj*VSTR + cf*4] = vp[cf];
            }
        }
        __syncthreads();
        if (rem > 0) {             // wave-uniform; barriers stay outside
            int jh1 = min(nk, half*64 + 64);
            for (int j = half*64; j < jh1; j++) {
                const float4* kr = (const float4*)&ks[j*KSTR];   // broadcast
                float4 k0 = kr[0], k1 = kr[1], k2 = kr[2], k3 = kr[3];
                const float4* vp4 = (const float4*)&vs[j*VSTR + c4*16];
                float4 v0 = vp4[0], v1 = vp4[1], v2 = vp4[2], v3 = vp4[3];
                #pragma unroll
                for (int s = 0; s < NS; s++) {
                    float s0 = qr[s][0].x*k0.x + qr[s][0].y*k0.y + qr[s][0].z*k0.z + qr[s][0].w*k0.w;
                    float s1 = qr[s][1].x*k1.x + qr[s][1].y*k1.y + qr[s][1].z*k1.z + qr[s][1].w*k1.w;
                    float s2 = qr[s][2].x*k2.x + qr[s][2].y*k2.y + qr[s][2].z*k2.z + qr[s][2].w*k2.w;
                    float s3 = qr[s][3].x*k3.x + qr[s][3].y*k3.y + qr[s][3].z*k3.z + qr[s][3].w*k3.w;
                    float pw = __builtin_amdgcn_exp2f((s0 + s1) + (s2 + s3));
                    lsum[s] += pw;
                    o[s][0].x = fmaf(pw, v0.x, o[s][0].x); o[s][0].y = fmaf(pw, v0.y, o[s][0].y);
                    o[s][0].z = fmaf(pw, v0.z, o[s][0].z); o[s][0].w = fmaf(pw, v0.w, o[s][0].w);
                    o[s][1].x = fmaf(pw, v1.x, o[s][1].x); o[s][1].y = fmaf(pw, v1.y, o[s][1].y);
                    o[s][1].z = fmaf(pw, v1.z, o[s][1].z); o[s][1].w = fmaf(pw, v1.w, o[s][1].w);
                    o[s][2].x = fmaf(pw, v2.x, o[s][2].x); o[s][2].y = fmaf(pw, v2.y, o[s][2].y);
                    o[s][2].z = fmaf(pw, v2.z, o[s][2].z); o[s][2].w = fmaf(pw, v2.w, o[s][2].w);
                    o[s][3].x = fmaf(pw, v3.x, o[s][3].x); o[s][3].y = fmaf(pw, v3.y, o[s][3].y);
                    o[s][3].z = fmaf(pw, v3.z, o[s][3].z); o[s][3].w = fmaf(pw, v3.w, o[s][3].w);
                }
            }
        }
    }
    // ---- merge half-1 partials into half-0 via LDS (2 fixed rounds) ----
    #pragma unroll
    for (int s = 0; s < 2; s++) {
        __syncthreads();
        if (s < NS && half == 1 && qi[s] < S) {
            float4* wb = (float4*)&vs[mx*16];
            wb[0]=o[s][0]; wb[1]=o[s][1]; wb[2]=o[s][2]; wb[3]=o[s][3];
            if (c4 == 0) lsm[qd] = lsum[s];
        }
        __syncthreads();
        if (s < NS && half == 0 && qi[s] < S) {
            const float4* rb = (const float4*)&vs[mx*16];
            float4 p0 = rb[0], p1 = rb[1], p2 = rb[2], p3 = rb[3];
            o[s][0].x+=p0.x; o[s][0].y+=p0.y; o[s][0].z+=p0.z; o[s][0].w+=p0.w;
            o[s][1].x+=p1.x; o[s][1].y+=p1.y; o[s][1].z+=p1.z; o[s][1].w+=p1.w;
            o[s][2].x+=p2.x; o[s][2].y+=p2.y; o[s][2].z+=p2.z; o[s][2].w+=p2.w;
            o[s][3].x+=p3.x; o[s][3].y+=p3.y; o[s][3].z+=p3.z; o[s][3].w+=p3.w;
            lsum[s] += lsm[qd];
        }
    }
    if (half == 0) {
        #pragma unroll
        for (int s = 0; s < NS; s++) {
            if (qi[s] < S) {
                float inv = 1.f / lsum[s];
                #pragma unroll
                for (int i = 0; i < 4; i++) {
                    o[s][i].x*=inv; o[s][i].y*=inv; o[s][i].z*=inv; o[s][i].w*=inv;
                }
                if (MODE == 1) {
                    float4* ap = (float4*)&acc[((size_t)h*Bn*Ln + b*Ln + iqr[s])*Cn + c4*16];
                    ap[0]=o[s][0]; ap[1]=o[s][1]; ap[2]=o[s][2]; ap[3]=o[s][3];
                } else {
                    float* ap = &acc[((size_t)b*Ln + iqr[s])*Cn + c4*16];
                    #pragma unroll
                    for (int i = 0; i < 4; i++) {
                        atomicAdd(&ap[4*i+0], (&o[s][i].x)[0]);
                        atomicAdd(&ap[4*i+1], (&o[s][i].x)[1]);
                        atomicAdd(&ap[4*i+2], (&o[s][i].x)[2]);
                        atomicAdd(&ap[4*i+3], (&o[s][i].x)[3]);
                    }
                }
            }
        }
    }
}

// 512 blocks x 512 threads: one block per (bh,u); intra-block key split
template<int MODE>
__global__ __launch_bounds__(512, 4) void attn_kernel(
        const float* __restrict__ q, const float* __restrict__ k,
        const float* __restrict__ v, const int* __restrict__ hidx,
        float* __restrict__ acc) {
    __shared__ int list[MAXS];
    __shared__ float ks[CH2*KSTR];
    __shared__ float vs[CH2*VSTR];
    __shared__ float lsm[64];
    __shared__ int wtot[8];
    int blk = blockIdx.x;          // = bh*NB + u
    int u  = blk & (NB-1);
    int bh = blk >> 5;
    int b  = bh >> 2;
    int h  = bh & 3;
    int tid = threadIdx.x;

    // ---- deterministic ascending bucket list via 8-wave scan (R10-proven) ----
    const int4* hp4 = (const int4*)(&hidx[bh*Ln] + tid*8);
    int hv[8];
    {
        int4 t0 = hp4[0], t1 = hp4[1];
        hv[0]=t0.x; hv[1]=t0.y; hv[2]=t0.z; hv[3]=t0.w;
        hv[4]=t1.x; hv[5]=t1.y; hv[6]=t1.z; hv[7]=t1.w;
    }
    int myCnt = 0;
    #pragma unroll
    for (int t = 0; t < 8; t++) myCnt += (hv[t] == u);
    int lane = tid & 63, wv = tid >> 6;
    int pre = myCnt;
    #pragma unroll
    for (int d = 1; d < 64; d <<= 1) {
        int t = __shfl_up(pre, d, 64);
        if (lane >= d) pre += t;
    }
    if (lane == 63) wtot[wv] = pre;
    __syncthreads();
    int base = 0, Sall = 0;
    #pragma unroll
    for (int w = 0; w < 8; w++) {
        base += (w < wv) ? wtot[w] : 0;
        Sall += wtot[w];
    }
    int S = min(Sall, MAXS);
    int excl = base + pre - myCnt;
    #pragma unroll
    for (int t = 0; t < 8; t++) {
        if (hv[t] == u) {
            if (excl < MAXS) list[excl] = tid*8 + t;
            excl++;
        }
    }
    __syncthreads();

    int half = wv >> 2;            // key half
    int wq0 = (wv & 3) * 16;       // first quad of this wave (pair-uniform)
    for (int qbase = 0; qbase < S; qbase += 128) {
        int rem = S - qbase - wq0;
        // pair-uniform NS; all instances have identical barrier counts
        if (rem > 64) attn_pass<2,MODE>(qbase,S,b,h,half,rem,tid,list,ks,vs,lsm,q,k,v,acc);
        else          attn_pass<1,MODE>(qbase,S,b,h,half,rem,tid,list,ks,vs,lsm,q,k,v,acc);
    }
}

// 512 blocks: (pos-group of 64) x (channel half of 32); wave og handles 8 ch
template<int MODE>
__global__ __launch_bounds__(256) void outconv_kernel(
        const float* __restrict__ acc, const float* __restrict__ Wo,
        const float* __restrict__ bo, const float* __restrict__ gamma,
        const float* __restrict__ x, float* __restrict__ y) {
    __shared__ float sWt[Cn*32];   // [c][oo] this half's 32 channels
    __shared__ float sb[32];
    int tid = threadIdx.x;
    int half = blockIdx.x & 1;
    int pg   = blockIdx.x >> 1;
    for (int idx = tid; idx < Cn*32; idx += 256) {
        int oo = idx & 31, c = idx >> 5;
        sWt[c*32 + oo] = Wo[(half*32 + oo)*Cn + c];
    }
    if (tid < 32) sb[tid] = bo[half*32 + tid];
    __syncthreads();
    float g = gamma[0];
    int p = tid & 63, og = tid >> 6;
    int gp = pg * 64 + p;
    int b = gp >> 12, l = gp & (Ln - 1);
    int oo0 = og * 8;
    float val[8];
    #pragma unroll
    for (int i = 0; i < 8; i++) val[i] = sb[oo0 + i];
    const float4* ap0 = (const float4*)&acc[(size_t)gp*Cn];
    #pragma unroll
    for (int c4 = 0; c4 < 16; c4++) {
        float4 t = ap0[c4];
        if (MODE == 1) {
            float4 t1 = ap0[(size_t)ACCSZ/4   + c4];
            float4 t2 = ap0[(size_t)ACCSZ/4*2 + c4];
            float4 t3 = ap0[(size_t)ACCSZ/4*3 + c4];
            t.x += t1.x + t2.x + t3.x; t.y += t1.y + t2.y + t3.y;
            t.z += t1.z + t2.z + t3.z; t.w += t1.w + t2.w + t3.w;
        }
        float a0 = t.x*0.25f, a1 = t.y*0.25f, a2 = t.z*0.25f, a3 = t.w*0.25f;
        const float* w0 = &sWt[(c4*4+0)*32 + oo0];
        const float* w1 = &sWt[(c4*4+1)*32 + oo0];
        const float* w2 = &sWt[(c4*4+2)*32 + oo0];
        const float* w3 = &sWt[(c4*4+3)*32 + oo0];
        #pragma unroll
        for (int i = 0; i < 8; i++) {
            val[i] = fmaf(w0[i], a0, val[i]);
            val[i] = fmaf(w1[i], a1, val[i]);
            val[i] = fmaf(w2[i], a2, val[i]);
            val[i] = fmaf(w3[i], a3, val[i]);
        }
    }
    #pragma unroll
    for (int i = 0; i < 8; i++) {
        int o = half*32 + oo0 + i;
        float yv = fmaf(g, val[i], x[(b*Cn + o)*Ln + l]);
        y[(b*Cn + o)*Ln + l] = yv;             // coalesced in p
    }
}

// 256 blocks = (c, part); plain-store partials (no memset, no atomics)
__global__ __launch_bounds__(256) void stats_kernel(
        const float* __restrict__ y, float* __restrict__ ssumP, float* __restrict__ ssqP) {
    int c = blockIdx.x >> 2;       // channel
    int part = blockIdx.x & 3;     // batch index
    int tid = threadIdx.x;
    const float4* yp = (const float4*)&y[(part*Cn + c)*Ln];
    float s = 0.f, s2 = 0.f;
    #pragma unroll
    for (int i = 0; i < 4; i++) {
        float4 t = yp[i*256 + tid];
        s  += t.x + t.y + t.z + t.w;
        s2 += t.x*t.x + t.y*t.y + t.z*t.z + t.w*t.w;
    }
    #pragma unroll
    for (int w = 1; w < 64; w <<= 1) {
        s  += __shfl_xor(s,  w, 64);
        s2 += __shfl_xor(s2, w, 64);
    }
    __shared__ float rs[4], rs2[4];
    int wv = tid >> 6;
    if ((tid & 63) == 0) { rs[wv] = s; rs2[wv] = s2; }
    __syncthreads();
    if (tid == 0) {
        ssumP[blockIdx.x] = rs[0]+rs[1]+rs[2]+rs[3];
        ssqP[blockIdx.x]  = rs2[0]+rs2[1]+rs2[2]+rs2[3];
    }
}

__global__ __launch_bounds__(256) void norm_kernel(
        const float* __restrict__ y,
        const float* __restrict__ ssumP, const float* __restrict__ ssqP,
        const float* __restrict__ bnw, const float* __restrict__ bnb,
        float* __restrict__ out) {
    int idx = blockIdx.x * 256 + threadIdx.x;  // float4 index
    int flat = idx * 4;
    int c = (flat / Ln) & 63;
    float s = 0.f, s2 = 0.f;
    #pragma unroll
    for (int hh = 0; hh < 4; hh++) { s += ssumP[c*4+hh]; s2 += ssqP[c*4+hh]; }
    const float n = (float)(Bn*Ln);
    float mu = s / n;
    float var = s2 / n - mu*mu;
    float is = rsqrtf(var + EPSV);
    float w = is * bnw[c];
    float bb = bnb[c] - mu * w;
    float4 t = ((const float4*)y)[idx];
    float4 r;
    r.x = t.x*w + bb; r.y = t.y*w + bb; r.z = t.z*w + bb; r.w = t.w*w + bb;
    ((float4*)out)[idx] = r;
}

extern "C" void kernel_launch(void* const* d_in, const int* in_sizes, int n_in,
                              void* d_out, int out_size, void* d_ws, size_t ws_size,
                              hipStream_t stream) {
    const float* x    = (const float*)d_in[0];
    const int*   hidx = (const int*)  d_in[1];
    const float* Wq   = (const float*)d_in[2];
    const float* bq   = (const float*)d_in[3];
    const float* Wk   = (const float*)d_in[4];
    const float* bk   = (const float*)d_in[5];
    const float* Wv   = (const float*)d_in[6];
    const float* bv   = (const float*)d_in[7];
    const float* Wo   = (const float*)d_in[8];
    const float* bo   = (const float*)d_in[9];
    const float* gam  = (const float*)d_in[10];
    const float* bnw  = (const float*)d_in[11];
    const float* bnb  = (const float*)d_in[12];
    float* out = (float*)d_out;

    float* ws  = (float*)d_ws;
    float* q   = ws;
    float* k   = ws + OFF_K;
    float* v   = ws + OFF_V;
    float* acc = ws + OFF_ACC;
    float* y   = ws;            // overlays q/k/v after attn

    const size_t bigNeed = ((size_t)OFF_ACC + 4*(size_t)ACCSZ + 512) * sizeof(float);
    bool big = ws_size >= bigNeed;
    float* ssumP = acc + (big ? 4*(size_t)ACCSZ : (size_t)ACCSZ);
    float* ssqP  = ssumP + 256;

    proj_kernel<<<Bn*Ln/64*3, 256, 0, stream>>>(x, Wq, bq, Wk, bk, Wv, bv, q, k, v);
    if (big) {
        attn_kernel<1><<<NBH*NB, 512, 0, stream>>>(q, k, v, hidx, acc);
        outconv_kernel<1><<<Bn*Ln/64*2, 256, 0, stream>>>(acc, Wo, bo, gam, x, y);
    } else {
        hipMemsetAsync(acc, 0, (size_t)ACCSZ*sizeof(float), stream);
        attn_kernel<0><<<NBH*NB, 512, 0, stream>>>(q, k, v, hidx, acc);
        outconv_kernel<0><<<Bn*Ln/64*2, 256, 0, stream>>>(acc, Wo, bo, gam, x, y);
    }
    stats_kernel<<<Cn*4, 256, 0, stream>>>(y, ssumP, ssqP);
    norm_kernel<<<Bn*Cn*Ln/4/256, 256, 0, stream>>>(y, ssumP, ssqP, bnw, bnb, out);
}

// Round 15
// 190.056 us; speedup vs baseline: 3.3451x; 1.0535x over previous
//
#include <hip/hip_runtime.h>
#include <math.h>

#define Bn 4
#define Cn 64
#define Ln 4096
#define CQ 16
#define NH 4
#define NB 32
#define EPSV 1e-5f

#define MAXS 384    // max bucket size (mean 128, sigma ~11)
#define CH2 64      // staged key chunk
#define KSTR 20     // ks row stride (floats)
#define VSTR2 36    // vs row stride (floats) for the 32-channel half

#define QSZ   (Bn*Ln*CQ)      // 262144 floats
#define VSZ   (Bn*Ln*Cn)      // 1048576 floats
#define ACCSZ (Bn*Ln*Cn)
#define NBH   (Bn*NH)         // 16

// layout (float units): [q][k][v][acc x4|x1][ssumP(256)][ssqP(256)]
#define OFF_K   QSZ
#define OFF_V   (2*QSZ)
#define OFF_ACC (2*QSZ + VSZ)

#define LOG2E 1.44269504088896f

// 768 blocks: (pos-group of 64) x (row-third of 32); og owns 8 rows
__global__ __launch_bounds__(256) void proj_kernel(
        const float* __restrict__ x,
        const float* __restrict__ Wq, const float* __restrict__ bq,
        const float* __restrict__ Wk, const float* __restrict__ bk,
        const float* __restrict__ Wv, const float* __restrict__ bv,
        float* __restrict__ q, float* __restrict__ k, float* __restrict__ v) {
    __shared__ float sWt[Cn*32];   // [c][rr]: this third's 32 rows
    __shared__ float sb[32];
    int tid = threadIdx.x;
    int third = blockIdx.x % 3;
    int pg    = blockIdx.x / 3;
    int rbase = third * 32;
    for (int idx = tid; idx < Cn*32; idx += 256) {
        int rr = idx & 31, c = idx >> 5;
        int r = rbase + rr;
        float w;
        if (r < 16)      w = Wq[r*Cn + c];
        else if (r < 32) w = Wk[(r-16)*Cn + c];
        else             w = Wv[(r-32)*Cn + c];
        sWt[c*32 + rr] = w;
    }
    if (tid < 32) {
        int r = rbase + tid;
        sb[tid] = (r < 16) ? bq[r] : (r < 32 ? bk[r-16] : bv[r-32]);
    }
    __syncthreads();
    int p = tid & 63, og = tid >> 6;       // og uniform per wave
    int gp = pg * 64 + p;                  // flattened position b*L + l
    int b = gp >> 12, l = gp & (Ln - 1);
    const float* xp = &x[b*Cn*Ln + l];
    int rr0 = og * 8;
    float val[8];
    #pragma unroll
    for (int i = 0; i < 8; i++) val[i] = sb[rr0 + i];
    #pragma unroll
    for (int c0 = 0; c0 < Cn; c0 += 8) {
        float xv[8];
        #pragma unroll
        for (int i = 0; i < 8; i++) xv[i] = xp[(c0 + i)*Ln];   // coalesced in p
        #pragma unroll
        for (int i = 0; i < 8; i++) {
            const float* wrow = &sWt[(c0 + i)*32 + rr0];       // LDS broadcast
            #pragma unroll
            for (int j = 0; j < 8; j++) val[j] = fmaf(wrow[j], xv[i], val[j]);
        }
    }
    int f = third*8 + og*2;                // wave-uniform; never straddles q/k/v
    float4 t0 = make_float4(val[0], val[1], val[2], val[3]);
    float4 t1 = make_float4(val[4], val[5], val[6], val[7]);
    float4* q4 = (float4*)&q[gp*CQ];
    float4* k4 = (float4*)&k[gp*CQ];
    float4* v4 = (float4*)&v[gp*Cn];
    if (f < 4)      { q4[f]   = t0; q4[f+1] = t1; }
    else if (f < 8) { k4[f-4] = t0; k4[f-3] = t1; }
    else            { v4[f-8] = t0; v4[f-7] = t1; }
}

// sweep all keys for NS queries/quad (stride 64); this block owns a 32-channel
// half: quad-lane c4 accumulates 8 channels (half*32 + c4*8 ..+7).
template<int NS, int MODE>
__device__ __forceinline__ void attn_pass(
        int qbase, int S, int b, int h, int half, int tid,
        const int* list, float* ks, float* vs,
        const float* __restrict__ q, const float* __restrict__ k,
        const float* __restrict__ v, float* __restrict__ acc) {
    int qd = tid >> 2, c4 = tid & 3;
    float4 qr[NS][4];
    float4 o[NS][2];               // 8 channels per lane
    float lsum[NS];
    int qi[NS], iqr[NS];
    #pragma unroll
    for (int s = 0; s < NS; s++) {
        qi[s] = qbase + 64*s + qd;
        iqr[s] = 0;
        lsum[s] = 0.f;
        o[s][0] = make_float4(0.f,0.f,0.f,0.f);
        o[s][1] = make_float4(0.f,0.f,0.f,0.f);
        if (qi[s] < S) {
            iqr[s] = list[qi[s]];
            const float4* qp = (const float4*)&q[((size_t)b*Ln + iqr[s])*CQ];
            #pragma unroll
            for (int i = 0; i < 4; i++) {
                float4 t = qp[i];   // pre-scale: exp(s) == exp2(s*log2e)
                t.x*=LOG2E; t.y*=LOG2E; t.z*=LOG2E; t.w*=LOG2E;
                qr[s][i] = t;
            }
        } else {
            #pragma unroll
            for (int i = 0; i < 4; i++) qr[s][i] = make_float4(0.f,0.f,0.f,0.f);
        }
    }
    for (int cc = 0; cc < S; cc += CH2) {
        int nk = min(CH2, S - cc);
        __syncthreads();           // previous chunk fully consumed
        {   // stage K chunk: nk rows x 16 floats, one b128 per thread
            int jj = tid >> 2, cf = tid & 3;
            if (jj < nk) {
                const float4* kp = (const float4*)&k[((size_t)b*Ln + list[cc+jj])*CQ];
                *(float4*)&ks[jj*KSTR + cf*4] = kp[cf];
            }
        }
        #pragma unroll
        for (int uu = 0; uu < 2; uu++) {   // stage V half-chunk: nk rows x 32 f
            int idx = uu*256 + tid;
            int jj = idx >> 3, cf = idx & 7;
            if (jj < nk) {
                const float4* vp = (const float4*)&v[((size_t)b*Ln + list[cc+jj])*Cn + half*32];
                *(float4*)&vs[jj*VSTR2 + cf*4] = vp[cf];
            }
        }
        __syncthreads();
        for (int j = 0; j < nk; j++) {
            const float4* kr = (const float4*)&ks[j*KSTR];   // broadcast
            float4 k0 = kr[0], k1 = kr[1], k2 = kr[2], k3 = kr[3];
            const float4* vp4 = (const float4*)&vs[j*VSTR2 + c4*8];
            float4 v0 = vp4[0], v1 = vp4[1];
            #pragma unroll
            for (int s = 0; s < NS; s++) {
                float s0 = qr[s][0].x*k0.x + qr[s][0].y*k0.y + qr[s][0].z*k0.z + qr[s][0].w*k0.w;
                float s1 = qr[s][1].x*k1.x + qr[s][1].y*k1.y + qr[s][1].z*k1.z + qr[s][1].w*k1.w;
                float s2 = qr[s][2].x*k2.x + qr[s][2].y*k2.y + qr[s][2].z*k2.z + qr[s][2].w*k2.w;
                float s3 = qr[s][3].x*k3.x + qr[s][3].y*k3.y + qr[s][3].z*k3.z + qr[s][3].w*k3.w;
                float pw = __builtin_amdgcn_exp2f((s0 + s1) + (s2 + s3));
                lsum[s] += pw;
                o[s][0].x = fmaf(pw, v0.x, o[s][0].x); o[s][0].y = fmaf(pw, v0.y, o[s][0].y);
                o[s][0].z = fmaf(pw, v0.z, o[s][0].z); o[s][0].w = fmaf(pw, v0.w, o[s][0].w);
                o[s][1].x = fmaf(pw, v1.x, o[s][1].x); o[s][1].y = fmaf(pw, v1.y, o[s][1].y);
                o[s][1].z = fmaf(pw, v1.z, o[s][1].z); o[s][1].w = fmaf(pw, v1.w, o[s][1].w);
            }
        }
    }
    #pragma unroll
    for (int s = 0; s < NS; s++) {
        if (qi[s] < S) {
            float inv = 1.f / lsum[s];   // identical across the quad
            o[s][0].x*=inv; o[s][0].y*=inv; o[s][0].z*=inv; o[s][0].w*=inv;
            o[s][1].x*=inv; o[s][1].y*=inv; o[s][1].z*=inv; o[s][1].w*=inv;
            if (MODE == 1) {
                float4* ap = (float4*)&acc[((size_t)h*Bn*Ln + b*Ln + iqr[s])*Cn + half*32 + c4*8];
                ap[0] = o[s][0]; ap[1] = o[s][1];
            } else {
                float* ap = &acc[((size_t)b*Ln + iqr[s])*Cn + half*32 + c4*8];
                atomicAdd(&ap[0], o[s][0].x); atomicAdd(&ap[1], o[s][0].y);
                atomicAdd(&ap[2], o[s][0].z); atomicAdd(&ap[3], o[s][0].w);
                atomicAdd(&ap[4], o[s][1].x); atomicAdd(&ap[5], o[s][1].y);
                atomicAdd(&ap[6], o[s][1].z); atomicAdd(&ap[7], o[s][1].w);
            }
        }
    }
}

// 1024 blocks: one per (bh,u,ch-half); disjoint plain stores, no atomics
template<int MODE>
__global__ __launch_bounds__(256, 4) void attn_kernel(
        const float* __restrict__ q, const float* __restrict__ k,
        const float* __restrict__ v, const int* __restrict__ hidx,
        float* __restrict__ acc) {
    __shared__ int list[MAXS];
    __shared__ float ks[CH2*KSTR];
    __shared__ float vs[CH2*VSTR2];
    __shared__ int wtot[4];
    int blk = blockIdx.x;
    int half = blk & 1;
    int rest = blk >> 1;           // = bh*NB + u
    int u  = rest & (NB-1);
    int bh = rest >> 5;
    int b  = bh >> 2;
    int h  = bh & 3;
    int tid = threadIdx.x;

    // ---- deterministic ascending bucket list via wave scan (R9-proven) ----
    const int4* hp4 = (const int4*)(&hidx[bh*Ln] + tid*16);
    int hv[16];
    #pragma unroll
    for (int t = 0; t < 4; t++) {
        int4 tmp = hp4[t];
        hv[t*4+0]=tmp.x; hv[t*4+1]=tmp.y; hv[t*4+2]=tmp.z; hv[t*4+3]=tmp.w;
    }
    int myCnt = 0;
    #pragma unroll
    for (int t = 0; t < 16; t++) myCnt += (hv[t] == u);
    int lane = tid & 63, wv = tid >> 6;
    int pre = myCnt;
    #pragma unroll
    for (int d = 1; d < 64; d <<= 1) {
        int t = __shfl_up(pre, d, 64);
        if (lane >= d) pre += t;
    }
    if (lane == 63) wtot[wv] = pre;
    __syncthreads();
    int base = 0;
    #pragma unroll
    for (int w = 0; w < 4; w++) base += (w < wv) ? wtot[w] : 0;
    int Sall = wtot[0] + wtot[1] + wtot[2] + wtot[3];
    int S = min(Sall, MAXS);
    int excl = base + pre - myCnt;
    #pragma unroll
    for (int t = 0; t < 16; t++) {
        if (hv[t] == u) {
            if (excl < MAXS) list[excl] = tid*16 + t;
            excl++;
        }
    }
    __syncthreads();

    // per-wave NS = ceil((S - qbase - wq0)/64), capped 3; 192 queries/sweep
    int wq0 = (tid >> 6) << 4;     // wave's first quad index
    for (int qbase = 0; qbase < S; qbase += 192) {
        int rem = S - qbase - wq0;
        // wave-uniform dispatch; all instances have identical barrier counts
        if (rem > 128)     attn_pass<3,MODE>(qbase,S,b,h,half,tid,list,ks,vs,q,k,v,acc);
        else if (rem > 64) attn_pass<2,MODE>(qbase,S,b,h,half,tid,list,ks,vs,q,k,v,acc);
        else               attn_pass<1,MODE>(qbase,S,b,h,half,tid,list,ks,vs,q,k,v,acc);
    }
}

// 512 blocks: (pos-group of 64) x (channel half of 32); wave og handles 8 ch
template<int MODE>
__global__ __launch_bounds__(256) void outconv_kernel(
        const float* __restrict__ acc, const float* __restrict__ Wo,
        const float* __restrict__ bo, const float* __restrict__ gamma,
        const float* __restrict__ x, float* __restrict__ y) {
    __shared__ float sWt[Cn*32];   // [c][oo] this half's 32 channels
    __shared__ float sb[32];
    int tid = threadIdx.x;
    int half = blockIdx.x & 1;
    int pg   = blockIdx.x >> 1;
    for (int idx = tid; idx < Cn*32; idx += 256) {
        int oo = idx & 31, c = idx >> 5;
        sWt[c*32 + oo] = Wo[(half*32 + oo)*Cn + c];
    }
    if (tid < 32) sb[tid] = bo[half*32 + tid];
    __syncthreads();
    float g = gamma[0];
    int p = tid & 63, og = tid >> 6;
    int gp = pg * 64 + p;
    int b = gp >> 12, l = gp & (Ln - 1);
    int oo0 = og * 8;
    float val[8];
    #pragma unroll
    for (int i = 0; i < 8; i++) val[i] = sb[oo0 + i];
    const float4* ap0 = (const float4*)&acc[(size_t)gp*Cn];
    #pragma unroll
    for (int c4 = 0; c4 < 16; c4++) {
        float4 t = ap0[c4];
        if (MODE == 1) {
            float4 t1 = ap0[(size_t)ACCSZ/4   + c4];
            float4 t2 = ap0[(size_t)ACCSZ/4*2 + c4];
            float4 t3 = ap0[(size_t)ACCSZ/4*3 + c4];
            t.x += t1.x + t2.x + t3.x; t.y += t1.y + t2.y + t3.y;
            t.z += t1.z + t2.z + t3.z; t.w += t1.w + t2.w + t3.w;
        }
        float a0 = t.x*0.25f, a1 = t.y*0.25f, a2 = t.z*0.25f, a3 = t.w*0.25f;
        const float* w0 = &sWt[(c4*4+0)*32 + oo0];
        const float* w1 = &sWt[(c4*4+1)*32 + oo0];
        const float* w2 = &sWt[(c4*4+2)*32 + oo0];
        const float* w3 = &sWt[(c4*4+3)*32 + oo0];
        #pragma unroll
        for (int i = 0; i < 8; i++) {
            val[i] = fmaf(w0[i], a0, val[i]);
            val[i] = fmaf(w1[i], a1, val[i]);
            val[i] = fmaf(w2[i], a2, val[i]);
            val[i] = fmaf(w3[i], a3, val[i]);
        }
    }
    #pragma unroll
    for (int i = 0; i < 8; i++) {
        int o = half*32 + oo0 + i;
        float yv = fmaf(g, val[i], x[(b*Cn + o)*Ln + l]);
        y[(b*Cn + o)*Ln + l] = yv;             // coalesced in p
    }
}

// 256 blocks = (c, part); plain-store partials (no memset, no atomics)
__global__ __launch_bounds__(256) void stats_kernel(
        const float* __restrict__ y, float* __restrict__ ssumP, float* __restrict__ ssqP) {
    int c = blockIdx.x >> 2;       // channel
    int part = blockIdx.x & 3;     // batch index
    int tid = threadIdx.x;
    const float4* yp = (const float4*)&y[(part*Cn + c)*Ln];
    float s = 0.f, s2 = 0.f;
    #pragma unroll
    for (int i = 0; i < 4; i++) {
        float4 t = yp[i*256 + tid];
        s  += t.x + t.y + t.z + t.w;
        s2 += t.x*t.x + t.y*t.y + t.z*t.z + t.w*t.w;
    }
    #pragma unroll
    for (int w = 1; w < 64; w <<= 1) {
        s  += __shfl_xor(s,  w, 64);
        s2 += __shfl_xor(s2, w, 64);
    }
    __shared__ float rs[4], rs2[4];
    int wv = tid >> 6;
    if ((tid & 63) == 0) { rs[wv] = s; rs2[wv] = s2; }
    __syncthreads();
    if (tid == 0) {
        ssumP[blockIdx.x] = rs[0]+rs[1]+rs[2]+rs[3];
        ssqP[blockIdx.x]  = rs2[0]+rs2[1]+rs2[2]+rs2[3];
    }
}

__global__ __launch_bounds__(256) void norm_kernel(
        const float* __restrict__ y,
        const float* __restrict__ ssumP, const float* __restrict__ ssqP,
        const float* __restrict__ bnw, const float* __restrict__ bnb,
        float* __restrict__ out) {
    int idx = blockIdx.x * 256 + threadIdx.x;  // float4 index
    int flat = idx * 4;
    int c = (flat / Ln) & 63;
    float s = 0.f, s2 = 0.f;
    #pragma unroll
    for (int hh = 0; hh < 4; hh++) { s += ssumP[c*4+hh]; s2 += ssqP[c*4+hh]; }
    const float n = (float)(Bn*Ln);
    float mu = s / n;
    float var = s2 / n - mu*mu;
    float is = rsqrtf(var + EPSV);
    float w = is * bnw[c];
    float bb = bnb[c] - mu * w;
    float4 t = ((const float4*)y)[idx];
    float4 r;
    r.x = t.x*w + bb; r.y = t.y*w + bb; r.z = t.z*w + bb; r.w = t.w*w + bb;
    ((float4*)out)[idx] = r;
}

extern "C" void kernel_launch(void* const* d_in, const int* in_sizes, int n_in,
                              void* d_out, int out_size, void* d_ws, size_t ws_size,
                              hipStream_t stream) {
    const float* x    = (const float*)d_in[0];
    const int*   hidx = (const int*)  d_in[1];
    const float* Wq   = (const float*)d_in[2];
    const float* bq   = (const float*)d_in[3];
    const float* Wk   = (const float*)d_in[4];
    const float* bk   = (const float*)d_in[5];
    const float* Wv   = (const float*)d_in[6];
    const float* bv   = (const float*)d_in[7];
    const float* Wo   = (const float*)d_in[8];
    const float* bo   = (const float*)d_in[9];
    const float* gam  = (const float*)d_in[10];
    const float* bnw  = (const float*)d_in[11];
    const float* bnb  = (const float*)d_in[12];
    float* out = (float*)d_out;

    float* ws  = (float*)d_ws;
    float* q   = ws;
    float* k   = ws + OFF_K;
    float* v   = ws + OFF_V;
    float* acc = ws + OFF_ACC;
    float* y   = ws;            // overlays q/k/v after attn

    const size_t bigNeed = ((size_t)OFF_ACC + 4*(size_t)ACCSZ + 512) * sizeof(float);
    bool big = ws_size >= bigNeed;
    float* ssumP = acc + (big ? 4*(size_t)ACCSZ : (size_t)ACCSZ);
    float* ssqP  = ssumP + 256;

    proj_kernel<<<Bn*Ln/64*3, 256, 0, stream>>>(x, Wq, bq, Wk, bk, Wv, bv, q, k, v);
    if (big) {
        attn_kernel<1><<<NBH*NB*2, 256, 0, stream>>>(q, k, v, hidx, acc);
        outconv_kernel<1><<<Bn*Ln/64*2, 256, 0, stream>>>(acc, Wo, bo, gam, x, y);
    } else {
        hipMemsetAsync(acc, 0, (size_t)ACCSZ*sizeof(float), stream);
        attn_kernel<0><<<NBH*NB*2, 256, 0, stream>>>(q, k, v, hidx, acc);
        outconv_kernel<0><<<Bn*Ln/64*2, 256, 0, stream>>>(acc, Wo, bo, gam, x, y);
    }
    stats_kernel<<<Cn*4, 256, 0, stream>>>(y, ssumP, ssqP);
    norm_kernel<<<Bn*Cn*Ln/4/256, 256, 0, stream>>>(y, ssumP, ssqP, bnw, bnb, out);
}

// Round 16
// 169.250 us; speedup vs baseline: 3.7563x; 1.1229x over previous
//
#include <hip/hip_runtime.h>
#include <math.h>

#define Bn 4
#define Cn 64
#define Ln 4096
#define CQ 16
#define NH 4
#define NB 32
#define EPSV 1e-5f

#define MAXS 384    // max bucket size (mean 128, sigma ~11)
#define CH2 64      // staged key chunk
#define KSTR 20     // ks row stride (floats)
#define VSTR 64     // vs row stride (floats)

#define QSZ   (Bn*Ln*CQ)      // 262144 floats
#define VSZ   (Bn*Ln*Cn)      // 1048576 floats
#define ACCSZ (Bn*Ln*Cn)
#define NBH   (Bn*NH)         // 16

// layout (float units): [q][k][v][acc x4|x1][ssumP(256)][ssqP(256)]
#define OFF_K   QSZ
#define OFF_V   (2*QSZ)
#define OFF_ACC (2*QSZ + VSZ)

#define LOG2E 1.44269504088896f

// 768 blocks: (pos-group of 64) x (row-third of 32); og owns 8 rows
__global__ __launch_bounds__(256) void proj_kernel(
        const float* __restrict__ x,
        const float* __restrict__ Wq, const float* __restrict__ bq,
        const float* __restrict__ Wk, const float* __restrict__ bk,
        const float* __restrict__ Wv, const float* __restrict__ bv,
        float* __restrict__ q, float* __restrict__ k, float* __restrict__ v) {
    __shared__ float sWt[Cn*32];   // [c][rr]: this third's 32 rows
    __shared__ float sb[32];
    int tid = threadIdx.x;
    int third = blockIdx.x % 3;
    int pg    = blockIdx.x / 3;
    int rbase = third * 32;
    for (int idx = tid; idx < Cn*32; idx += 256) {
        int rr = idx & 31, c = idx >> 5;
        int r = rbase + rr;
        float w;
        if (r < 16)      w = Wq[r*Cn + c];
        else if (r < 32) w = Wk[(r-16)*Cn + c];
        else             w = Wv[(r-32)*Cn + c];
        sWt[c*32 + rr] = w;
    }
    if (tid < 32) {
        int r = rbase + tid;
        sb[tid] = (r < 16) ? bq[r] : (r < 32 ? bk[r-16] : bv[r-32]);
    }
    __syncthreads();
    int p = tid & 63, og = tid >> 6;       // og uniform per wave
    int gp = pg * 64 + p;                  // flattened position b*L + l
    int b = gp >> 12, l = gp & (Ln - 1);
    const float* xp = &x[b*Cn*Ln + l];
    int rr0 = og * 8;
    float val[8];
    #pragma unroll
    for (int i = 0; i < 8; i++) val[i] = sb[rr0 + i];
    #pragma unroll
    for (int c0 = 0; c0 < Cn; c0 += 8) {
        float xv[8];
        #pragma unroll
        for (int i = 0; i < 8; i++) xv[i] = xp[(c0 + i)*Ln];   // coalesced in p
        #pragma unroll
        for (int i = 0; i < 8; i++) {
            const float* wrow = &sWt[(c0 + i)*32 + rr0];       // LDS broadcast
            #pragma unroll
            for (int j = 0; j < 8; j++) val[j] = fmaf(wrow[j], xv[i], val[j]);
        }
    }
    int f = third*8 + og*2;                // wave-uniform; never straddles q/k/v
    float4 t0 = make_float4(val[0], val[1], val[2], val[3]);
    float4 t1 = make_float4(val[4], val[5], val[6], val[7]);
    float4* q4 = (float4*)&q[gp*CQ];
    float4* k4 = (float4*)&k[gp*CQ];
    float4* v4 = (float4*)&v[gp*Cn];
    if (f < 4)      { q4[f]   = t0; q4[f+1] = t1; }
    else if (f < 8) { k4[f-4] = t0; k4[f-3] = t1; }
    else            { v4[f-8] = t0; v4[f-7] = t1; }
}

// sweep; quad qd (= tid>>2, 0..63) holds NS queries qi = qbase + 64*s + qd
template<int NS, int MODE>
__device__ __forceinline__ void attn_pass(
        int qbase, int S, int b, int h, int tid, int rem,
        const int* list, float* ks, float* vs,
        const float* __restrict__ q, const float* __restrict__ k,
        const float* __restrict__ v, float* __restrict__ acc) {
    int qd = tid >> 2, c4 = tid & 3;
    float4 qr[NS][4];
    float4 o[NS][4];
    float lsum[NS];
    int qi[NS], iqr[NS];
    #pragma unroll
    for (int s = 0; s < NS; s++) {
        qi[s] = qbase + 64*s + qd;
        iqr[s] = 0;
        lsum[s] = 0.f;
        #pragma unroll
        for (int i = 0; i < 4; i++) o[s][i] = make_float4(0.f,0.f,0.f,0.f);
        if (qi[s] < S) {
            iqr[s] = list[qi[s]];
            const float4* qp = (const float4*)&q[((size_t)b*Ln + iqr[s])*CQ];
            #pragma unroll
            for (int i = 0; i < 4; i++) {
                float4 t = qp[i];   // pre-scale: exp(s) == exp2(s*log2e)
                t.x*=LOG2E; t.y*=LOG2E; t.z*=LOG2E; t.w*=LOG2E;
                qr[s][i] = t;
            }
        } else {
            #pragma unroll
            for (int i = 0; i < 4; i++) qr[s][i] = make_float4(0.f,0.f,0.f,0.f);
        }
    }
    for (int cc = 0; cc < S; cc += CH2) {
        int nk = min(CH2, S - cc);
        __syncthreads();           // previous chunk fully consumed
        {   // stage K chunk: nk rows x 16 floats, one b128 per thread
            int jj = tid >> 2, cf = tid & 3;
            if (jj < nk) {
                const float4* kp = (const float4*)&k[((size_t)b*Ln + list[cc+jj])*CQ];
                *(float4*)&ks[jj*KSTR + cf*4] = kp[cf];
            }
        }
        #pragma unroll
        for (int uu = 0; uu < 4; uu++) {   // stage V chunk: nk rows x 64 floats
            int idx = uu*256 + tid;
            int jj = idx >> 4, cf = idx & 15;
            if (jj < nk) {
                const float4* vp = (const float4*)&v[((size_t)b*Ln + list[cc+jj])*Cn];
                *(float4*)&vs[jj*VSTR + cf*4] = vp[cf];
            }
        }
        __syncthreads();
        if (rem > 0) {             // wave-uniform skip (no barriers in j-loop)
            for (int j = 0; j < nk; j++) {
                const float4* kr = (const float4*)&ks[j*KSTR];   // broadcast
                float4 k0 = kr[0], k1 = kr[1], k2 = kr[2], k3 = kr[3];
                const float4* vp4 = (const float4*)&vs[j*VSTR + c4*16];
                float4 v0 = vp4[0], v1 = vp4[1], v2 = vp4[2], v3 = vp4[3];
                #pragma unroll
                for (int s = 0; s < NS; s++) {
                    float s0 = qr[s][0].x*k0.x + qr[s][0].y*k0.y + qr[s][0].z*k0.z + qr[s][0].w*k0.w;
                    float s1 = qr[s][1].x*k1.x + qr[s][1].y*k1.y + qr[s][1].z*k1.z + qr[s][1].w*k1.w;
                    float s2 = qr[s][2].x*k2.x + qr[s][2].y*k2.y + qr[s][2].z*k2.z + qr[s][2].w*k2.w;
                    float s3 = qr[s][3].x*k3.x + qr[s][3].y*k3.y + qr[s][3].z*k3.z + qr[s][3].w*k3.w;
                    float pw = __builtin_amdgcn_exp2f((s0 + s1) + (s2 + s3));
                    lsum[s] += pw;
                    o[s][0].x = fmaf(pw, v0.x, o[s][0].x); o[s][0].y = fmaf(pw, v0.y, o[s][0].y);
                    o[s][0].z = fmaf(pw, v0.z, o[s][0].z); o[s][0].w = fmaf(pw, v0.w, o[s][0].w);
                    o[s][1].x = fmaf(pw, v1.x, o[s][1].x); o[s][1].y = fmaf(pw, v1.y, o[s][1].y);
                    o[s][1].z = fmaf(pw, v1.z, o[s][1].z); o[s][1].w = fmaf(pw, v1.w, o[s][1].w);
                    o[s][2].x = fmaf(pw, v2.x, o[s][2].x); o[s][2].y = fmaf(pw, v2.y, o[s][2].y);
                    o[s][2].z = fmaf(pw, v2.z, o[s][2].z); o[s][2].w = fmaf(pw, v2.w, o[s][2].w);
                    o[s][3].x = fmaf(pw, v3.x, o[s][3].x); o[s][3].y = fmaf(pw, v3.y, o[s][3].y);
                    o[s][3].z = fmaf(pw, v3.z, o[s][3].z); o[s][3].w = fmaf(pw, v3.w, o[s][3].w);
                }
            }
        }
    }
    #pragma unroll
    for (int s = 0; s < NS; s++) {
        if (qi[s] < S) {
            float inv = 1.f / lsum[s];   // identical across the quad
            #pragma unroll
            for (int i = 0; i < 4; i++) {
                o[s][i].x*=inv; o[s][i].y*=inv; o[s][i].z*=inv; o[s][i].w*=inv;
            }
            if (MODE == 1) {
                float4* ap = (float4*)&acc[((size_t)h*Bn*Ln + b*Ln + iqr[s])*Cn + c4*16];
                ap[0]=o[s][0]; ap[1]=o[s][1]; ap[2]=o[s][2]; ap[3]=o[s][3];
            } else {
                float* ap = &acc[((size_t)b*Ln + iqr[s])*Cn + c4*16];
                #pragma unroll
                for (int i = 0; i < 4; i++) {
                    atomicAdd(&ap[4*i+0], (&o[s][i].x)[0]);
                    atomicAdd(&ap[4*i+1], (&o[s][i].x)[1]);
                    atomicAdd(&ap[4*i+2], (&o[s][i].x)[2]);
                    atomicAdd(&ap[4*i+3], (&o[s][i].x)[3]);
                }
            }
        }
    }
}

// 512 blocks: one per (bh,u) bucket; 256 threads = 64 quads, NS<=3 slots each
template<int MODE>
__global__ __launch_bounds__(256, 2) void attn_kernel(
        const float* __restrict__ q, const float* __restrict__ k,
        const float* __restrict__ v, const int* __restrict__ hidx,
        float* __restrict__ acc) {
    __shared__ int list[MAXS];
    __shared__ float ks[CH2*KSTR];
    __shared__ float vs[CH2*VSTR];
    __shared__ int wtot[4];
    int blk = blockIdx.x;          // = bh*NB + u
    int u  = blk & (NB-1);
    int bh = blk >> 5;
    int b  = bh >> 2;
    int h  = bh & 3;
    int tid = threadIdx.x;

    // ---- deterministic ascending bucket list via wave scan ----
    const int4* hp4 = (const int4*)(&hidx[bh*Ln] + tid*16);
    int hv[16];
    #pragma unroll
    for (int t = 0; t < 4; t++) {
        int4 tmp = hp4[t];
        hv[t*4+0]=tmp.x; hv[t*4+1]=tmp.y; hv[t*4+2]=tmp.z; hv[t*4+3]=tmp.w;
    }
    int myCnt = 0;
    #pragma unroll
    for (int t = 0; t < 16; t++) myCnt += (hv[t] == u);
    int lane = tid & 63, wv = tid >> 6;
    int pre = myCnt;
    #pragma unroll
    for (int d = 1; d < 64; d <<= 1) {
        int t = __shfl_up(pre, d, 64);
        if (lane >= d) pre += t;
    }
    if (lane == 63) wtot[wv] = pre;
    __syncthreads();
    int base = 0;
    #pragma unroll
    for (int w = 0; w < 4; w++) base += (w < wv) ? wtot[w] : 0;
    int Sall = wtot[0] + wtot[1] + wtot[2] + wtot[3];
    int S = min(Sall, MAXS);
    int excl = base + pre - myCnt;
    #pragma unroll
    for (int t = 0; t < 16; t++) {
        if (hv[t] == u) {
            if (excl < MAXS) list[excl] = tid*16 + t;
            excl++;
        }
    }
    __syncthreads();

    // per-wave NS = ceil((S - qbase - wq0)/64), capped 3; 192 queries/sweep
    int wq0 = (tid >> 6) << 4;     // wave's first quad index
    for (int qbase = 0; qbase < S; qbase += 192) {
        int rem = S - qbase - wq0;
        // wave-uniform dispatch; all instances have identical barrier counts
        if (rem > 128)     attn_pass<3,MODE>(qbase,S,b,h,tid,rem,list,ks,vs,q,k,v,acc);
        else if (rem > 64) attn_pass<2,MODE>(qbase,S,b,h,tid,rem,list,ks,vs,q,k,v,acc);
        else               attn_pass<1,MODE>(qbase,S,b,h,tid,rem,list,ks,vs,q,k,v,acc);
    }
}

// 512 blocks x 32 positions; acc summed+staged in LDS once (no redundant reads)
template<int MODE>
__global__ __launch_bounds__(256) void outconv_kernel(
        const float* __restrict__ acc, const float* __restrict__ Wo,
        const float* __restrict__ bo, const float* __restrict__ gamma,
        const float* __restrict__ x, float* __restrict__ y) {
    __shared__ float sWt[Cn*Cn];     // [c][o], 16 KB
    __shared__ float sA[Cn*33];      // [c][p] stride 33, conflict-free
    __shared__ float sb[Cn];
    int tid = threadIdx.x;
    int pg = blockIdx.x;             // 32 positions per block
    for (int idx = tid; idx < Cn*Cn; idx += 256) {
        int o = idx & 63, c = idx >> 6;
        sWt[c*Cn + o] = Wo[o*Cn + c];
    }
    if (tid < Cn) sb[tid] = bo[tid];
    // stage summed acc: 32 pos x 64 ch; thread loads f4 idx {tid, tid+256}
    const float4* a4 = (const float4*)&acc[(size_t)pg*32*Cn];
    #pragma unroll
    for (int r = 0; r < 2; r++) {
        int idx = r*256 + tid;       // p = idx>>4, c4 = idx&15
        int p = idx >> 4, c0 = (idx & 15) * 4;
        float4 t = a4[idx];
        if (MODE == 1) {
            float4 t1 = a4[(size_t)ACCSZ/4   + idx];
            float4 t2 = a4[(size_t)ACCSZ/4*2 + idx];
            float4 t3 = a4[(size_t)ACCSZ/4*3 + idx];
            t.x += t1.x + t2.x + t3.x; t.y += t1.y + t2.y + t3.y;
            t.z += t1.z + t2.z + t3.z; t.w += t1.w + t2.w + t3.w;
        }
        sA[(c0+0)*33 + p] = t.x*0.25f;   // banks 2 lanes/bank: free
        sA[(c0+1)*33 + p] = t.y*0.25f;
        sA[(c0+2)*33 + p] = t.z*0.25f;
        sA[(c0+3)*33 + p] = t.w*0.25f;
    }
    __syncthreads();
    float g = gamma[0];
    int p = tid & 31, og = tid >> 5;    // 8 groups x 8 channels
    int gp = pg * 32 + p;
    int b = gp >> 12, l = gp & (Ln - 1);
    int o0 = og * 8;
    float val[8];
    #pragma unroll
    for (int i = 0; i < 8; i++) val[i] = sb[o0 + i];
    #pragma unroll
    for (int c = 0; c < Cn; c++) {
        float av = sA[c*33 + p];        // p-major: conflict-free
        const float* wrow = &sWt[c*Cn + o0];   // broadcast
        #pragma unroll
        for (int i = 0; i < 8; i++) val[i] = fmaf(wrow[i], av, val[i]);
    }
    #pragma unroll
    for (int i = 0; i < 8; i++) {
        int o = o0 + i;
        float yv = fmaf(g, val[i], x[(b*Cn + o)*Ln + l]);
        y[(b*Cn + o)*Ln + l] = yv;
    }
}

// 256 blocks = (c, part); plain-store partials (no memset, no atomics)
__global__ __launch_bounds__(256) void stats_kernel(
        const float* __restrict__ y, float* __restrict__ ssumP, float* __restrict__ ssqP) {
    int c = blockIdx.x >> 2;       // channel
    int part = blockIdx.x & 3;     // batch index
    int tid = threadIdx.x;
    const float4* yp = (const float4*)&y[(part*Cn + c)*Ln];
    float s = 0.f, s2 = 0.f;
    #pragma unroll
    for (int i = 0; i < 4; i++) {
        float4 t = yp[i*256 + tid];
        s  += t.x + t.y + t.z + t.w;
        s2 += t.x*t.x + t.y*t.y + t.z*t.z + t.w*t.w;
    }
    #pragma unroll
    for (int w = 1; w < 64; w <<= 1) {
        s  += __shfl_xor(s,  w, 64);
        s2 += __shfl_xor(s2, w, 64);
    }
    __shared__ float rs[4], rs2[4];
    int wv = tid >> 6;
    if ((tid & 63) == 0) { rs[wv] = s; rs2[wv] = s2; }
    __syncthreads();
    if (tid == 0) {
        ssumP[blockIdx.x] = rs[0]+rs[1]+rs[2]+rs[3];
        ssqP[blockIdx.x]  = rs2[0]+rs2[1]+rs2[2]+rs2[3];
    }
}

__global__ __launch_bounds__(256) void norm_kernel(
        const float* __restrict__ y,
        const float* __restrict__ ssumP, const float* __restrict__ ssqP,
        const float* __restrict__ bnw, const float* __restrict__ bnb,
        float* __restrict__ out) {
    int idx = blockIdx.x * 256 + threadIdx.x;  // float4 index
    int flat = idx * 4;
    int c = (flat / Ln) & 63;
    float s = 0.f, s2 = 0.f;
    #pragma unroll
    for (int hh = 0; hh < 4; hh++) { s += ssumP[c*4+hh]; s2 += ssqP[c*4+hh]; }
    const float n = (float)(Bn*Ln);
    float mu = s / n;
    float var = s2 / n - mu*mu;
    float is = rsqrtf(var + EPSV);
    float w = is * bnw[c];
    float bb = bnb[c] - mu * w;
    float4 t = ((const float4*)y)[idx];
    float4 r;
    r.x = t.x*w + bb; r.y = t.y*w + bb; r.z = t.z*w + bb; r.w = t.w*w + bb;
    ((float4*)out)[idx] = r;
}

extern "C" void kernel_launch(void* const* d_in, const int* in_sizes, int n_in,
                              void* d_out, int out_size, void* d_ws, size_t ws_size,
                              hipStream_t stream) {
    const float* x    = (const float*)d_in[0];
    const int*   hidx = (const int*)  d_in[1];
    const float* Wq   = (const float*)d_in[2];
    const float* bq   = (const float*)d_in[3];
    const float* Wk   = (const float*)d_in[4];
    const float* bk   = (const float*)d_in[5];
    const float* Wv   = (const float*)d_in[6];
    const float* bv   = (const float*)d_in[7];
    const float* Wo   = (const float*)d_in[8];
    const float* bo   = (const float*)d_in[9];
    const float* gam  = (const float*)d_in[10];
    const float* bnw  = (const float*)d_in[11];
    const float* bnb  = (const float*)d_in[12];
    float* out = (float*)d_out;

    float* ws  = (float*)d_ws;
    float* q   = ws;
    float* k   = ws + OFF_K;
    float* v   = ws + OFF_V;
    float* acc = ws + OFF_ACC;
    float* y   = ws;            // overlays q/k/v after attn

    const size_t bigNeed = ((size_t)OFF_ACC + 4*(size_t)ACCSZ + 512) * sizeof(float);
    bool big = ws_size >= bigNeed;
    float* ssumP = acc + (big ? 4*(size_t)ACCSZ : (size_t)ACCSZ);
    float* ssqP  = ssumP + 256;

    proj_kernel<<<Bn*Ln/64*3, 256, 0, stream>>>(x, Wq, bq, Wk, bk, Wv, bv, q, k, v);
    if (big) {
        attn_kernel<1><<<NBH*NB, 256, 0, stream>>>(q, k, v, hidx, acc);
        outconv_kernel<1><<<Bn*Ln/32, 256, 0, stream>>>(acc, Wo, bo, gam, x, y);
    } else {
        hipMemsetAsync(acc, 0, (size_t)ACCSZ*sizeof(float), stream);
        attn_kernel<0><<<NBH*NB, 256, 0, stream>>>(q, k, v, hidx, acc);
        outconv_kernel<0><<<Bn*Ln/32, 256, 0, stream>>>(acc, Wo, bo, gam, x, y);
    }
    stats_kernel<<<Cn*4, 256, 0, stream>>>(y, ssumP, ssqP);
    norm_kernel<<<Bn*Cn*Ln/4/256, 256, 0, stream>>>(y, ssumP, ssqP, bnw, bnb, out);
}